// Round 5
// baseline (26.843 us; speedup 1.0000x reference)
//
#include <hip/hip_runtime.h>

#define FS    5
#define NTAP  25
#define Bc    8
#define Cc    32
#define CH    16                    // channels per block (half of Cc)
#define Hc    128
#define Wc    128
#define HW    (Hc * Wc)

#define TH    8
#define TW    64
#define HALO_H (TH + 4)             // 12
#define HALO_W (TW + 4)             // 68
#define PLANE  (HALO_H * HALO_W)    // 816 floats per channel
#define NPAIR  (PLANE / 2)          // 408 float2 per channel
#define LDS_BYTES (CH * PLANE * 4)  // 52224 B -> 2 blocks/CU

// One block = one 8x64 tile of one image, ONE 16-channel half.
// Stage own 16 halo planes in LDS; filter-gen reads own half from LDS and
// the other half's center pixels straight from global (L2/L3-resident);
// apply = 5x5 stencil over own 16 channels, 2 px/thread (float2).
// Single barrier; gen-other global loads issued after it.
__global__ __launch_bounds__(256, 2) void ppdfn_fused(
    const float* __restrict__ x, const float* __restrict__ wg,
    const float* __restrict__ bg, float* __restrict__ out)
{
    extern __shared__ float xs[];   // [CH][PLANE]
    const int tid = threadIdx.x;
    const int bid = blockIdx.x;     // 0..511

    // XCD-aware decode: consecutive linear ids round-robin XCDs (bid&7);
    // give each XCD one contiguous 16-row h-band (2 ht values) so halo
    // re-reads hit that XCD's L2 (working set ~2.6 MB < 4 MB).
    const int g  = bid & 7;
    const int m  = bid >> 3;        // 0..63
    const int ht = (g << 1) + (m & 1);      // 0..15
    const int wt = (m >> 1) & 1;            // 0..1
    const int c0 = ((m >> 2) & 1) * CH;     // own channel base: 0 or 16
    const int b  = m >> 3;                  // 0..7

    const int h0 = ht * TH, w0 = wt * TW;

    // ---- staging addresses: 2 float2 slots per thread (408 pairs/plane) ----
    const int ip0 = tid;                    // pair 0..255
    const int ip1 = tid + 256;              // pair 256..407 (tid < 152)
    const bool s1ok = (ip1 < NPAIR);
    int go0, go1; float m0, m1;
    {
        const int r  = ip0 / 34, pc = ip0 - r * 34;
        const int gh = h0 - 2 + r, gw = w0 - 2 + 2 * pc;
        const bool v = ((unsigned)gh < (unsigned)Hc) && ((unsigned)gw < (unsigned)Wc);
        m0  = v ? 1.0f : 0.0f;
        go0 = v ? gh * Wc + gw : 0;         // clamp OOB to safe addr, mask value
    }
    {
        const int r  = ip1 / 34, pc = ip1 - r * 34;
        const int gh = h0 - 2 + r, gw = w0 - 2 + 2 * pc;
        const bool v = s1ok && ((unsigned)gh < (unsigned)Hc) && ((unsigned)gw < (unsigned)Wc);
        m1  = v ? 1.0f : 0.0f;
        go1 = v ? gh * Wc + gw : 0;
    }

    const float* xb = x + (size_t)b * Cc * HW;      // batch base
    const float* xo = xb + (size_t)c0 * HW;         // own-half base

    // ---- stage own 16 channels: issue ALL loads, then all LDS writes ----
    float2 ra[CH], rb[CH];
#pragma unroll
    for (int c = 0; c < CH; ++c) {
        ra[c] = *reinterpret_cast<const float2*>(xo + (size_t)c * HW + go0);
        rb[c] = *reinterpret_cast<const float2*>(xo + (size_t)c * HW + go1);
    }
#pragma unroll
    for (int c = 0; c < CH; ++c) {
        float2 va = make_float2(ra[c].x * m0, ra[c].y * m0);
        *reinterpret_cast<float2*>(xs + c * PLANE + 2 * ip0) = va;
        if (s1ok) {
            float2 vb = make_float2(rb[c].x * m1, rb[c].y * m1);
            *reinterpret_cast<float2*>(xs + c * PLANE + 2 * ip1) = vb;
        }
    }
    __syncthreads();

    // ---- per-pixel coords for gen/apply (2 px per thread) ----
    const int ty = tid >> 5;        // 0..7
    const int tx = tid & 31;        // 0..31
    const int w2 = tx * 2;

    // issue other-half center loads NOW (after barrier, overlap with gen-own)
    const int oc = c0 ^ CH;
    const float* xc_other = xb + (size_t)oc * HW + (h0 + ty) * Wc + (w0 + w2);
    float2 xv_o[CH];
#pragma unroll
    for (int c = 0; c < CH; ++c)
        xv_o[c] = *reinterpret_cast<const float2*>(xc_other + (size_t)c * HW);

    // ---- filter generation (25 taps x 2 px) ----
    float fx[NTAP], fy[NTAP];
#pragma unroll
    for (int t = 0; t < NTAP; ++t) { const float bv = bg[t]; fx[t] = bv; fy[t] = bv; }

#pragma unroll 4
    for (int c = 0; c < CH; ++c) {          // own half from LDS
        const float2 xv = *reinterpret_cast<const float2*>(
            xs + c * PLANE + (ty + 2) * HALO_W + (w2 + 2));
        const float* wrow = wg + (c0 + c);
#pragma unroll
        for (int t = 0; t < NTAP; ++t) {
            const float wv = wrow[t * Cc];  // wave-uniform -> s_load
            fx[t] = fmaf(wv, xv.x, fx[t]);
            fy[t] = fmaf(wv, xv.y, fy[t]);
        }
    }
#pragma unroll 4
    for (int c = 0; c < CH; ++c) {          // other half from global regs
        const float2 xv = xv_o[c];
        const float* wrow = wg + (oc + c);
#pragma unroll
        for (int t = 0; t < NTAP; ++t) {
            const float wv = wrow[t * Cc];
            fx[t] = fmaf(wv, xv.x, fx[t]);
            fy[t] = fmaf(wv, xv.y, fy[t]);
        }
    }

    // ---- apply 5x5 dynamic filter over own 16 channels ----
    float* ob = out + ((size_t)b * Cc + c0) * HW + (h0 + ty) * Wc + (w0 + w2);
#pragma unroll 2
    for (int c = 0; c < CH; ++c) {
        const float* p = xs + c * PLANE + ty * HALO_W + w2;
        float ax = 0.f, ay = 0.f;
#pragma unroll
        for (int di = 0; di < FS; ++di) {
            const float* row = p + di * HALO_W;
            const float2 s01 = *reinterpret_cast<const float2*>(row);
            const float2 s23 = *reinterpret_cast<const float2*>(row + 2);
            const float2 s45 = *reinterpret_cast<const float2*>(row + 4);
            const float s0 = s01.x, s1 = s01.y, s2 = s23.x,
                        s3 = s23.y, s4 = s45.x, s5 = s45.y;
            ax = fmaf(fx[di * FS + 0], s0, ax);  ay = fmaf(fy[di * FS + 0], s1, ay);
            ax = fmaf(fx[di * FS + 1], s1, ax);  ay = fmaf(fy[di * FS + 1], s2, ay);
            ax = fmaf(fx[di * FS + 2], s2, ax);  ay = fmaf(fy[di * FS + 2], s3, ay);
            ax = fmaf(fx[di * FS + 3], s3, ax);  ay = fmaf(fy[di * FS + 3], s4, ay);
            ax = fmaf(fx[di * FS + 4], s4, ax);  ay = fmaf(fy[di * FS + 4], s5, ay);
        }
        *reinterpret_cast<float2*>(ob + (size_t)c * HW) = make_float2(ax, ay);
    }
}

extern "C" void kernel_launch(void* const* d_in, const int* in_sizes, int n_in,
                              void* d_out, int out_size, void* d_ws, size_t ws_size,
                              hipStream_t stream) {
    const float* x  = (const float*)d_in[0];
    const float* wg = (const float*)d_in[1];
    const float* bg = (const float*)d_in[2];
    float* out = (float*)d_out;

    ppdfn_fused<<<dim3(512), 256, LDS_BYTES, stream>>>(x, wg, bg, out);
}

// Round 6
// 23.238 us; speedup vs baseline: 1.1552x; 1.1552x over previous
//
#include <hip/hip_runtime.h>

#define FS    5
#define NTAP  25
#define Bc    8
#define Cc    32
#define Hc    128
#define Wc    128
#define HW    (Hc * Wc)

#define TH      8
#define TW      64
#define HALO_H  12                    // TH + 4
#define HALO_W  72                    // [w0-4, w0+68): float4-aligned left edge
#define PLANE   (HALO_H * HALO_W)     // 864 floats
#define LDS_FLOATS (Cc * PLANE)       // 27648
#define LDS_BYTES  (LDS_FLOATS * 4)   // 110592 -> 1 block/CU
#define F4_PER_PLANE (PLANE / 4)      // 216
#define F4_TOTAL     (Cc * F4_PER_PLANE)   // 6912
#define INSTR_TOTAL  (F4_TOTAL / 64)       // 108 dwordx4 DMA instrs per block
#define NWAVE        4
#define INSTR_PER_WAVE (INSTR_TOTAL / NWAVE)  // 27

// zero-initialized device global: OOB lanes' DMA source (16B aligned)
__device__ __attribute__((aligned(16))) float ZERO4[4];

__device__ __forceinline__ void gload_lds16(const float* g, float* lds) {
    __builtin_amdgcn_global_load_lds(
        (const __attribute__((address_space(1))) void*)g,
        (__attribute__((address_space(3))) void*)lds, 16, 0, 0);
}

// One block = one 8x64 tile of one image, ALL 32 channels staged via
// global_load_lds DMA (no VGPR round-trip, 27 loads in flight per wave).
// LDS layout [c][12][72]; col L maps to global col (w0-4+L).
// Phase 2: per-thread filter gen (2 px) from LDS, wg via uniform s_loads.
// Phase 3: per-channel 5x5 apply from LDS, float2 stores. One barrier.
__global__ __launch_bounds__(256, 1) void ppdfn_fused(
    const float* __restrict__ x, const float* __restrict__ wg,
    const float* __restrict__ bg, float* __restrict__ out)
{
    extern __shared__ float xs[];     // [Cc][HALO_H][HALO_W]

    const int tid  = threadIdx.x;
    const int lane = tid & 63;
    const int wv   = tid >> 6;        // 0..3
    const int ht   = blockIdx.x;      // 0..15
    const int wt   = blockIdx.y;      // 0..1
    const int b    = blockIdx.z;      // 0..7
    const int h0   = ht * TH;
    const int w0   = wt * TW;

    const float* xb = x + (size_t)b * Cc * HW;

    // ---- phase 1: async DMA stage, 27 dwordx4 per wave ----
    // flat float4 index f -> (c, r, c4); every float4 is fully valid or
    // only needs zeros (halo width 72 guarantees no mixed-partial case).
    const int f_base = wv * (INSTR_PER_WAVE * 64) + lane;
#pragma unroll
    for (int k = 0; k < INSTR_PER_WAVE; ++k) {
        const int f  = f_base + k * 64;
        const int c  = f / F4_PER_PLANE;            // /216 (magic mul)
        const int rm = f - c * F4_PER_PLANE;
        const int r  = rm / 18;
        const int c4 = rm - r * 18;
        const int gh = h0 - 2 + r;
        const int gw = w0 - 4 + 4 * c4;
        const bool v = ((unsigned)gh < (unsigned)Hc) &&
                       ((unsigned)gw <= (unsigned)(Wc - 4));
        const float* src = v ? (xb + (size_t)c * HW + gh * Wc + gw) : ZERO4;
        gload_lds16(src, xs + (size_t)(wv * INSTR_PER_WAVE + k) * 256);
    }
    asm volatile("s_waitcnt vmcnt(0)" ::: "memory");
    __syncthreads();

    // ---- phase 2: filter generation, 2 px per thread ----
    const int ty = tid >> 5;          // 0..7
    const int tx = tid & 31;          // 0..31
    const int w2 = tx * 2;

    float fx[NTAP], fy[NTAP];
#pragma unroll
    for (int t = 0; t < NTAP; ++t) { const float bv = bg[t]; fx[t] = bv; fy[t] = bv; }

#pragma unroll 4
    for (int c = 0; c < Cc; ++c) {
        // output px (h0+ty, w0+w2) -> lds row ty+2, col w2+4
        const float2 xv = *reinterpret_cast<const float2*>(
            xs + c * PLANE + (ty + 2) * HALO_W + (w2 + 4));
#pragma unroll
        for (int t = 0; t < NTAP; ++t) {
            const float wv_ = wg[t * Cc + c];     // wave-uniform -> s_load
            fx[t] = fmaf(wv_, xv.x, fx[t]);
            fy[t] = fmaf(wv_, xv.y, fy[t]);
        }
    }

    // ---- phase 3: apply 5x5 over all 32 channels ----
    float* ob = out + (size_t)b * Cc * HW + (h0 + ty) * Wc + (w0 + w2);
#pragma unroll 2
    for (int c = 0; c < Cc; ++c) {
        // leftmost tap of px0: global col w0+w2-2 -> lds col w2+2 (8B aligned)
        const float* p = xs + c * PLANE + ty * HALO_W + (w2 + 2);
        float ax = 0.f, ay = 0.f;
#pragma unroll
        for (int di = 0; di < FS; ++di) {
            const float* row = p + di * HALO_W;
            const float2 s01 = *reinterpret_cast<const float2*>(row);
            const float2 s23 = *reinterpret_cast<const float2*>(row + 2);
            const float2 s45 = *reinterpret_cast<const float2*>(row + 4);
            const float s0 = s01.x, s1 = s01.y, s2 = s23.x,
                        s3 = s23.y, s4 = s45.x, s5 = s45.y;
            ax = fmaf(fx[di * FS + 0], s0, ax);  ay = fmaf(fy[di * FS + 0], s1, ay);
            ax = fmaf(fx[di * FS + 1], s1, ax);  ay = fmaf(fy[di * FS + 1], s2, ay);
            ax = fmaf(fx[di * FS + 2], s2, ax);  ay = fmaf(fy[di * FS + 2], s3, ay);
            ax = fmaf(fx[di * FS + 3], s3, ax);  ay = fmaf(fy[di * FS + 3], s4, ay);
            ax = fmaf(fx[di * FS + 4], s4, ax);  ay = fmaf(fy[di * FS + 4], s5, ay);
        }
        *reinterpret_cast<float2*>(ob + (size_t)c * HW) = make_float2(ax, ay);
    }
}

extern "C" void kernel_launch(void* const* d_in, const int* in_sizes, int n_in,
                              void* d_out, int out_size, void* d_ws, size_t ws_size,
                              hipStream_t stream) {
    const float* x  = (const float*)d_in[0];
    const float* wg = (const float*)d_in[1];
    const float* bg = (const float*)d_in[2];
    float* out = (float*)d_out;

    ppdfn_fused<<<dim3(Hc / TH, Wc / TW, Bc), 256, LDS_BYTES, stream>>>(
        x, wg, bg, out);
}